// Round 1
// baseline (1972.675 us; speedup 1.0000x reference)
//
#include <hip/hip_runtime.h>
#include <math.h>

#define BATCH 8
#define CH    256
#define HWN   4096
#define DQK   16

#define QT 64   // query tile per block
#define MT 32   // key tile per iteration
#define HSTRIDE 260  // 256 + 4 pad (keeps 16B alignment for b128, breaks bank stride)
#define PSTRIDE 72   // 64 + 8 pad

// ---------------- fused projection kernel ----------------
// cat = [Wf; Wg; Wh] (288x256) @ x[b] (256x4096) + bias -> f[16], g[16], h[256]
// block: 256 thr; block tile 64 rows x 128 px; thread tile 16 rows x 2 px
// row group (16 rows) never straddles f/g/h boundaries (tr multiple of 16).
__global__ __launch_bounds__(256) void proj_kernel(
    const float* __restrict__ x,
    const float* __restrict__ Wf, const float* __restrict__ bf,
    const float* __restrict__ Wg, const float* __restrict__ bg,
    const float* __restrict__ Wh, const float* __restrict__ bh,
    float* __restrict__ f, float* __restrict__ g, float* __restrict__ h)
{
    const int t    = threadIdx.x;
    const int row0 = blockIdx.x * 64;          // 5 blocks: rows [0,288) w/ guard
    const int p0   = blockIdx.y * 128;
    const int b    = blockIdx.z;

    __shared__ float Xl[64][128];              // 32 KB

    const int tp  = (t & 63) * 2;              // pixel offset (lane-varying)
    const int tr  = (t >> 6) * 16;             // row offset (wave-uniform -> scalar W loads)
    const int row = row0 + tr;
    const bool valid = row < 288;

    const float* wbase; const float* bbase; float* obase;
    if (!valid)        { wbase = Wh;               bbase = bh;            obase = nullptr; }
    else if (row < 16) { wbase = Wf + row*CH;      bbase = bf + row;      obase = f + (size_t)(b*DQK + row)*HWN; }
    else if (row < 32) { wbase = Wg + (row-16)*CH; bbase = bg + (row-16); obase = g + (size_t)(b*DQK + (row-16))*HWN; }
    else               { wbase = Wh + (row-32)*CH; bbase = bh + (row-32); obase = h + (size_t)(b*CH  + (row-32))*HWN; }

    float acc[16][2];
    #pragma unroll
    for (int j = 0; j < 16; j++) { acc[j][0] = 0.f; acc[j][1] = 0.f; }

    for (int kc = 0; kc < CH; kc += 64) {
        __syncthreads();
        #pragma unroll
        for (int j = 0; j < 32; j++) {         // 8192 floats, coalesced
            int i = j*256 + t;
            int k = i >> 7, p = i & 127;
            Xl[k][p] = x[(size_t)(b*CH + kc + k)*HWN + p0 + p];
        }
        __syncthreads();
        for (int k = 0; k < 64; k++) {
            float xv0 = Xl[k][tp];
            float xv1 = Xl[k][tp+1];
            #pragma unroll
            for (int j = 0; j < 16; j++) {
                float wv = wbase[j*CH + kc + k];   // wave-uniform -> s_load
                acc[j][0] += wv * xv0;
                acc[j][1] += wv * xv1;
            }
        }
    }
    if (valid) {
        #pragma unroll
        for (int j = 0; j < 16; j++) {
            float bb = bbase[j];
            obase[(size_t)j*HWN + p0 + tp]     = acc[j][0] + bb;
            obase[(size_t)j*HWN + p0 + tp + 1] = acc[j][1] + bb;
        }
    }
}

// ---------------- flash attention kernel ----------------
// one block = (batch b, 64 queries). Iterate key tiles of 32.
// s[q][m] = sum_k g[k][q] f[k][m]; online softmax over m; acc[c][q] += p*h[c][m]
__global__ __launch_bounds__(256) void attn_kernel(
    const float* __restrict__ f, const float* __restrict__ g,
    const float* __restrict__ h, const float* __restrict__ x,
    const float* __restrict__ gamma_p, float* __restrict__ out)
{
    const int t  = threadIdx.x;
    const int q0 = blockIdx.x * QT;
    const int b  = blockIdx.y;

    __shared__ float g_l[DQK][QT];       // 4 KB
    __shared__ float f_l[DQK][MT];       // 2 KB
    __shared__ float h_l[MT][HSTRIDE];   // 33.3 KB, transposed [m][c]
    __shared__ float p_l[MT][PSTRIDE];   // 9.2 KB, [m][q]
    __shared__ float mi[QT], li[QT], al[QT];

    for (int i = t; i < DQK*QT; i += 256) {       // load query tile of g
        int k = i >> 6, q = i & 63;
        g_l[k][q] = g[(size_t)(b*DQK + k)*HWN + q0 + q];
    }
    if (t < QT) { mi[t] = -INFINITY; li[t] = 0.f; }

    // PV thread tile: 8 channels x 8 queries
    const int c0  = (t >> 3) * 8;
    const int qt0 = (t & 7) * 8;
    float acc[8][8];
    #pragma unroll
    for (int i = 0; i < 8; i++)
        #pragma unroll
        for (int j = 0; j < 8; j++) acc[i][j] = 0.f;

    // s-compute mapping: thread handles key sm, queries sq..sq+7
    const int sm = t & 31;
    const int sq = (t >> 5) * 8;

    for (int m0 = 0; m0 < HWN; m0 += MT) {
        __syncthreads();   // previous tile's h_l/p_l reads done
        for (int i = t; i < DQK*MT; i += 256) {
            int k = i >> 5, m = i & 31;
            f_l[k][m] = f[(size_t)(b*DQK + k)*HWN + m0 + m];
        }
        #pragma unroll
        for (int j = 0; j < 32; j++) {            // h tile, transposed into LDS
            int i = j*256 + t;
            int c = i >> 5, m = i & 31;
            h_l[m][c] = h[(size_t)(b*CH + c)*HWN + m0 + m];
        }
        __syncthreads();

        // ---- s tile: 64q x 32m, K=16 ----
        {
            float sv[8];
            #pragma unroll
            for (int j = 0; j < 8; j++) sv[j] = 0.f;
            #pragma unroll
            for (int k = 0; k < DQK; k++) {
                float fv = f_l[k][sm];
                #pragma unroll
                for (int j = 0; j < 8; j++) sv[j] += fv * g_l[k][sq + j];
            }
            #pragma unroll
            for (int j = 0; j < 8; j++) p_l[sm][sq + j] = sv[j];
        }
        __syncthreads();

        // ---- online softmax row update: thread q = t (first 64 threads) ----
        if (t < QT) {
            float rm = -INFINITY;
            #pragma unroll
            for (int m = 0; m < MT; m++) rm = fmaxf(rm, p_l[m][t]);
            float mold = mi[t];
            float mnew = fmaxf(mold, rm);
            float a  = __expf(mold - mnew);   // first tile: exp(-inf)=0
            float rs = 0.f;
            #pragma unroll
            for (int m = 0; m < MT; m++) {
                float pv = __expf(p_l[m][t] - mnew);
                p_l[m][t] = pv;
                rs += pv;
            }
            li[t] = li[t]*a + rs;
            mi[t] = mnew;
            al[t] = a;
        }
        __syncthreads();

        // ---- rescale + PV accumulate ----
        float av[8];
        #pragma unroll
        for (int j = 0; j < 8; j++) av[j] = al[qt0 + j];
        #pragma unroll
        for (int i = 0; i < 8; i++)
            #pragma unroll
            for (int j = 0; j < 8; j++) acc[i][j] *= av[j];

        for (int m = 0; m < MT; m++) {
            float hv[8], pv[8];
            #pragma unroll
            for (int i = 0; i < 8; i++) hv[i] = h_l[m][c0 + i];   // 2x ds_read_b128
            #pragma unroll
            for (int j = 0; j < 8; j++) pv[j] = p_l[m][qt0 + j];  // 2x ds_read_b128
            #pragma unroll
            for (int i = 0; i < 8; i++)
                #pragma unroll
                for (int j = 0; j < 8; j++) acc[i][j] += hv[i] * pv[j];
        }
    }

    __syncthreads();
    float inv[8];
    #pragma unroll
    for (int j = 0; j < 8; j++) inv[j] = 1.f / li[qt0 + j];
    const float gamma = *gamma_p;
    #pragma unroll
    for (int i = 0; i < 8; i++) {
        size_t base = (size_t)(b*CH + c0 + i)*HWN + q0 + qt0;
        #pragma unroll
        for (int j = 0; j < 8; j++) {
            out[base + j] = gamma * acc[i][j] * inv[j] + x[base + j];
        }
    }
}

extern "C" void kernel_launch(void* const* d_in, const int* in_sizes, int n_in,
                              void* d_out, int out_size, void* d_ws, size_t ws_size,
                              hipStream_t stream) {
    const float* x     = (const float*)d_in[0];
    const float* Wf    = (const float*)d_in[1];
    const float* bf    = (const float*)d_in[2];
    const float* Wg    = (const float*)d_in[3];
    const float* bg    = (const float*)d_in[4];
    const float* Wh    = (const float*)d_in[5];
    const float* bh    = (const float*)d_in[6];
    const float* gamma = (const float*)d_in[7];
    float* out = (float*)d_out;

    // ws layout (fp32): f[8][16][4096] | g[8][16][4096] | h[8][256][4096] = 37.75 MB
    float* f = (float*)d_ws;
    float* g = f + (size_t)BATCH*DQK*HWN;
    float* h = g + (size_t)BATCH*DQK*HWN;

    dim3 pg(5, 32, BATCH);     // 5 row-blocks (288 rows, guarded) x 32 px-blocks x B
    proj_kernel<<<pg, 256, 0, stream>>>(x, Wf, bf, Wg, bg, Wh, bh, f, g, h);

    dim3 ag(HWN/QT, BATCH);    // 64 query-tiles x 8 batches
    attn_kernel<<<ag, 256, 0, stream>>>(f, g, h, x, gamma, out);
}

// Round 2
// 448.641 us; speedup vs baseline: 4.3970x; 4.3970x over previous
//
#include <hip/hip_runtime.h>
#include <hip/hip_bf16.h>
#include <math.h>

#define BATCH 8
#define CH    256
#define HWN   4096
#define DQK   16
#define QT    64
#define MT    32

typedef __attribute__((ext_vector_type(8))) short short8;
typedef __attribute__((ext_vector_type(4))) float float4v;

__device__ __forceinline__ unsigned short f2bf(float f) {
    union { float f; unsigned int u; } v; v.f = f;
    unsigned int r = v.u + 0x7FFF + ((v.u >> 16) & 1);   // RNE
    return (unsigned short)(r >> 16);
}

// ---------------- fused projection: [Wf;Wg;Wh](288x256) @ x[b](256x4096) -> bf16 f,g,h ----------------
// block 256 thr; tile 64 rows x 256 px; thread tile 16 rows x 4 px (float4 LDS reads)
__global__ __launch_bounds__(256) void proj_kernel(
    const float* __restrict__ x,
    const float* __restrict__ Wf, const float* __restrict__ bf_,
    const float* __restrict__ Wg, const float* __restrict__ bg,
    const float* __restrict__ Wh, const float* __restrict__ bh,
    unsigned short* __restrict__ f, unsigned short* __restrict__ g,
    unsigned short* __restrict__ h)
{
    const int t    = threadIdx.x;
    const int row0 = blockIdx.x * 64;
    const int p0   = blockIdx.y * 256;
    const int b    = blockIdx.z;

    __shared__ float Xl[32][256];              // 32 KB

    const int tp  = (t & 63) * 4;
    const int tr  = (t >> 6) * 16;
    const int row = row0 + tr;
    const bool valid = row < 288;

    const float* wbase; const float* bbase; unsigned short* obase;
    if (!valid)        { wbase = Wh;               bbase = bh;             obase = nullptr; }
    else if (row < 16) { wbase = Wf + row*CH;      bbase = bf_ + row;      obase = f + (size_t)(b*DQK + row)*HWN; }
    else if (row < 32) { wbase = Wg + (row-16)*CH; bbase = bg + (row-16);  obase = g + (size_t)(b*DQK + (row-16))*HWN; }
    else               { wbase = Wh + (row-32)*CH; bbase = bh + (row-32);  obase = h + (size_t)(b*CH  + (row-32))*HWN; }

    float acc[16][4];
    #pragma unroll
    for (int j = 0; j < 16; j++)
        #pragma unroll
        for (int i = 0; i < 4; i++) acc[j][i] = 0.f;

    for (int kc = 0; kc < CH; kc += 32) {
        __syncthreads();
        #pragma unroll
        for (int j = 0; j < 32; j++) {
            int i = j*256 + t;
            int k = i >> 8, p = i & 255;
            Xl[k][p] = x[(size_t)(b*CH + kc + k)*HWN + p0 + p];
        }
        __syncthreads();
        for (int k = 0; k < 32; k++) {
            float4 xv = *(const float4*)&Xl[k][tp];
            #pragma unroll
            for (int j = 0; j < 16; j++) {
                float wv = wbase[j*CH + kc + k];           // wave-uniform -> scalar
                acc[j][0] += wv * xv.x;
                acc[j][1] += wv * xv.y;
                acc[j][2] += wv * xv.z;
                acc[j][3] += wv * xv.w;
            }
        }
    }
    if (valid) {
        #pragma unroll
        for (int j = 0; j < 16; j++) {
            float bb = bbase[j];
            unsigned int lo = (unsigned int)f2bf(acc[j][0] + bb) | ((unsigned int)f2bf(acc[j][1] + bb) << 16);
            unsigned int hi = (unsigned int)f2bf(acc[j][2] + bb) | ((unsigned int)f2bf(acc[j][3] + bb) << 16);
            *(uint2*)&obase[(size_t)j*HWN + p0 + tp] = make_uint2(lo, hi);
        }
    }
}

// ---------------- MFMA flash attention ----------------
// block = (batch, 64-query tile). 4 waves. Per m-tile (32 keys):
//   S = g^T f via 16x16x32 MFMA (K=16 zero-padded); p = exp(s) (no max-tracking:
//   |s| <= ~30 so exp fits fp32/bf16 comfortably); l[q] += row-sums;
//   O[c][q] += h[c][m] p[m][q] via 16x16x32 MFMA. Final: gamma*O/l + x.
// hA/pB/fB are LDS in MFMA-fragment order: [tile][lane][8 bf16] -> all b128, conflict-free.
__global__ __launch_bounds__(256) void attn_kernel(
    const unsigned short* __restrict__ f, const unsigned short* __restrict__ g,
    const unsigned short* __restrict__ h, const float* __restrict__ x,
    const float* __restrict__ gamma_p, float* __restrict__ out)
{
    const int t    = threadIdx.x;
    const int b    = blockIdx.x & 7;        // %8 -> XCD-pinned batch (L2 locality)
    const int q0   = (blockIdx.x >> 3) * QT;
    const int lane = t & 63;
    const int w    = t >> 6;                // wave 0..3
    const int l15  = lane & 15;
    const int quad = lane >> 4;

    __shared__ __align__(16) unsigned short hA[16][64][8];  // 16 KB: A-frags of h, ctile-major
    __shared__ __align__(16) unsigned short pB[4][64][8];   //  4 KB: B-frags of p, qtile-major
    __shared__ __align__(16) unsigned short fB[2][64][8];   //  2 KB: B-frags of f, msub-major
    __shared__ float l_l[QT];

    // init: l=0; fB zero (k>=16 half stays zero forever)
    if (t < QT) l_l[t] = 0.f;
    for (int i = t; i < 2*64*8; i += 256) ((unsigned short*)fB)[i] = 0;

    // g A-fragment (held in regs whole kernel): A[q=l15][k=quad*8+j], zeros for k>=16
    union { short8 v; unsigned short u[8]; } gfrag;
    #pragma unroll
    for (int j = 0; j < 8; j++) {
        int k = quad*8 + j;
        gfrag.u[j] = (k < DQK) ? g[(size_t)(b*DQK + k)*HWN + q0 + w*16 + l15] : (unsigned short)0;
    }

    float4v acc[4][4];
    #pragma unroll
    for (int i = 0; i < 4; i++)
        #pragma unroll
        for (int j = 0; j < 4; j++) acc[i][j] = (float4v){0.f,0.f,0.f,0.f};

    __syncthreads();

    for (int m0 = 0; m0 < HWN; m0 += MT) {
        // ---- stage h tile (256c x 32m bf16) into fragment layout ----
        #pragma unroll
        for (int it = 0; it < 4; it++) {
            int idx = it*256 + t;            // 0..1023
            int c = idx >> 2, ms = idx & 3;  // 8 bf16 at m = ms*8
            *(uint4*)&hA[c >> 4][ms*16 + (c & 15)][0] =
                *(const uint4*)&h[(size_t)(b*CH + c)*HWN + m0 + ms*8];
        }
        // ---- stage f tile (16k x 32m) into B-frag layout (k<16 half) ----
        if (t < 128) {
            int k = t >> 3, m = (t & 7) * 4;
            const unsigned short* src = &f[(size_t)(b*DQK + k)*HWN + m0 + m];
            #pragma unroll
            for (int i = 0; i < 4; i++) {
                int mm = m + i;
                fB[mm >> 4][(k >> 3)*16 + (mm & 15)][k & 7] = src[i];
            }
        }
        __syncthreads();

        // ---- S = g^T f : wave w computes its own 16q x 32m ----
        short8 fb0 = *(short8*)&fB[0][lane][0];
        short8 fb1 = *(short8*)&fB[1][lane][0];
        float4v s0 = {0.f,0.f,0.f,0.f}, s1 = {0.f,0.f,0.f,0.f};
        s0 = __builtin_amdgcn_mfma_f32_16x16x32_bf16(gfrag.v, fb0, s0, 0, 0, 0);
        s1 = __builtin_amdgcn_mfma_f32_16x16x32_bf16(gfrag.v, fb1, s1, 0, 0, 0);

        // p = exp(s); row-sums into l; p -> bf16 B-frags
        float pv0[4], pv1[4], rs[4];
        #pragma unroll
        for (int r = 0; r < 4; r++) {
            pv0[r] = __expf(s0[r]);
            pv1[r] = __expf(s1[r]);
            rs[r]  = pv0[r] + pv1[r];        // m and m+16
        }
        #pragma unroll
        for (int off = 1; off <= 8; off <<= 1)
            #pragma unroll
            for (int r = 0; r < 4; r++) rs[r] += __shfl_xor(rs[r], off, 64);
        if (l15 == 0) {
            #pragma unroll
            for (int r = 0; r < 4; r++) l_l[w*16 + quad*4 + r] += rs[r];
        }
        #pragma unroll
        for (int r = 0; r < 4; r++) {
            int q15 = quad*4 + r;
            pB[w][(l15 >> 3)*16 + q15][l15 & 7]       = f2bf(pv0[r]);  // m = l15
            pB[w][(2 + (l15 >> 3))*16 + q15][l15 & 7] = f2bf(pv1[r]);  // m = 16+l15
        }
        __syncthreads();

        // ---- PV: wave w covers c in [w*64, w*64+64) x all 64 q ----
        short8 bq[4];
        #pragma unroll
        for (int qt = 0; qt < 4; qt++) bq[qt] = *(short8*)&pB[qt][lane][0];
        #pragma unroll
        for (int ct = 0; ct < 4; ct++) {
            short8 af = *(short8*)&hA[w*4 + ct][lane][0];
            #pragma unroll
            for (int qt = 0; qt < 4; qt++)
                acc[ct][qt] = __builtin_amdgcn_mfma_f32_16x16x32_bf16(af, bq[qt], acc[ct][qt], 0, 0, 0);
        }
        __syncthreads();   // guard next iteration's restaging
    }

    // ---- epilogue: O = gamma * acc / l + x ----
    const float gamma = *gamma_p;
    float linv[4];
    #pragma unroll
    for (int qt = 0; qt < 4; qt++) linv[qt] = 1.f / l_l[qt*16 + l15];
    #pragma unroll
    for (int ct = 0; ct < 4; ct++) {
        #pragma unroll
        for (int r = 0; r < 4; r++) {
            int c = w*64 + ct*16 + quad*4 + r;
            size_t base = (size_t)(b*CH + c)*HWN + q0;
            #pragma unroll
            for (int qt = 0; qt < 4; qt++) {
                size_t o = base + qt*16 + l15;
                out[o] = gamma * acc[ct][qt][r] * linv[qt] + x[o];
            }
        }
    }
}

extern "C" void kernel_launch(void* const* d_in, const int* in_sizes, int n_in,
                              void* d_out, int out_size, void* d_ws, size_t ws_size,
                              hipStream_t stream) {
    const float* x     = (const float*)d_in[0];
    const float* Wf    = (const float*)d_in[1];
    const float* bf_   = (const float*)d_in[2];
    const float* Wg    = (const float*)d_in[3];
    const float* bg    = (const float*)d_in[4];
    const float* Wh    = (const float*)d_in[5];
    const float* bh    = (const float*)d_in[6];
    const float* gamma = (const float*)d_in[7];
    float* out = (float*)d_out;

    // ws (bf16): f[8][16][4096] | g[8][16][4096] | h[8][256][4096]  = 18.9 MB
    unsigned short* f = (unsigned short*)d_ws;
    unsigned short* g = f + (size_t)BATCH*DQK*HWN;
    unsigned short* h = g + (size_t)BATCH*DQK*HWN;

    dim3 pg(5, 16, BATCH);
    proj_kernel<<<pg, 256, 0, stream>>>(x, Wf, bf_, Wg, bg, Wh, bh, f, g, h);

    attn_kernel<<<dim3((HWN/QT)*BATCH), 256, 0, stream>>>(f, g, h, x, gamma, out);
}

// Round 3
// 444.758 us; speedup vs baseline: 4.4354x; 1.0087x over previous
//
#include <hip/hip_runtime.h>
#include <math.h>

#define BATCH 8
#define CH    256
#define HWN   4096
#define DQK   16
#define QT    64
#define MT    32

typedef __attribute__((ext_vector_type(8))) short short8;
typedef __attribute__((ext_vector_type(4))) float float4v;

__device__ __forceinline__ unsigned short f2bf(float f) {
    union { float f; unsigned int u; } v; v.f = f;
    unsigned int r = v.u + 0x7FFF + ((v.u >> 16) & 1);   // RNE
    return (unsigned short)(r >> 16);
}

// ---------------- kernel 0: cast W_cat = [Wf;Wg;Wh] to bf16, concat biases ----------------
__global__ __launch_bounds__(256) void wcast_kernel(
    const float* __restrict__ Wf, const float* __restrict__ bf_,
    const float* __restrict__ Wg, const float* __restrict__ bg,
    const float* __restrict__ Wh, const float* __restrict__ bh,
    unsigned short* __restrict__ Wbf, float* __restrict__ bcat)
{
    const int r = blockIdx.x;   // 288 rows
    const int t = threadIdx.x;  // 256 cols
    const float* src = (r < 16) ? (Wf + r*CH) : (r < 32) ? (Wg + (r-16)*CH) : (Wh + (r-32)*CH);
    Wbf[r*CH + t] = f2bf(src[t]);
    if (t == 0) bcat[r] = (r < 16) ? bf_[r] : (r < 32) ? bg[r-16] : bh[r-32];
}

// ---------------- kernel 1: MFMA projection ----------------
// C[288][4096] = Wbf[288][256] @ bf16(x)[256][4096] per batch; rows 0-15 -> f,
// 16-31 -> g, 32-287 -> h. Block: 64-px tile, all 288 rows; wave w owns px
// subtile w*16. Double-buffered LDS B-frags + register prefetch; A-frags read
// directly from L2-hot Wbf (no LDS).
__global__ __launch_bounds__(256) void proj_kernel(
    const float* __restrict__ x, const unsigned short* __restrict__ Wbf,
    const float* __restrict__ bcat,
    unsigned short* __restrict__ f, unsigned short* __restrict__ g,
    unsigned short* __restrict__ h)
{
    const int t    = threadIdx.x;
    const int px0  = blockIdx.x * 64;
    const int b    = blockIdx.y;
    const int lane = t & 63;
    const int w    = t >> 6;
    const int l15  = lane & 15;
    const int quad = lane >> 4;

    __shared__ __align__(16) unsigned short xB[2][4][64][8];  // 8 KB B-frags
    __shared__ float bs[288];
    for (int i = t; i < 288; i += 256) bs[i] = bcat[i];

    // per-kstep read map: 32 k-rows x 64 px, thread reads 2 float4
    const int rk  = t >> 3;          // local k row 0..31
    const int rpx = (t & 7) * 8;     // local px 0..56

    float4 ca, cb;                   // prefetch regs (8 floats)
    auto load_chunk = [&](int ks) {
        const float* xp = &x[(size_t)(b*CH + ks*32 + rk)*HWN + px0 + rpx];
        ca = *(const float4*)xp;
        cb = *(const float4*)(xp + 4);
    };
    auto write_chunk = [&](int buf) {
        float v[8] = {ca.x, ca.y, ca.z, ca.w, cb.x, cb.y, cb.z, cb.w};
        #pragma unroll
        for (int i = 0; i < 8; i++) {
            int px = rpx + i;
            xB[buf][px >> 4][(rk >> 3)*16 + (px & 15)][rk & 7] = f2bf(v[i]);
        }
    };

    float4v acc[18];
    #pragma unroll
    for (int rt = 0; rt < 18; rt++) acc[rt] = (float4v){0.f,0.f,0.f,0.f};

    load_chunk(0);
    write_chunk(0);
    load_chunk(1);

    const unsigned short* wbase = &Wbf[l15*CH + quad*8];

    for (int ks = 0; ks < 8; ks++) {
        int buf = ks & 1;
        // A: write tile ks+1 -> buf^1, prefetch tile ks+2
        write_chunk(buf ^ 1);
        load_chunk((ks + 2) & 7);
        __syncthreads();                               // C: staging visible
        // D: compute on buf
        short8 bfrag = *(short8*)&xB[buf][w][lane][0];
        #pragma unroll
        for (int rt = 0; rt < 18; rt++) {
            short8 afrag = *(const short8*)&wbase[rt*16*CH + ks*32];
            acc[rt] = __builtin_amdgcn_mfma_f32_16x16x32_bf16(afrag, bfrag, acc[rt], 0, 0, 0);
        }
        __syncthreads();                               // E: reads done (WAR)
    }

    // epilogue: bias + cast + store (C layout: col=l15 -> px, row=quad*4+r)
    #pragma unroll
    for (int rt = 0; rt < 18; rt++) {
        #pragma unroll
        for (int r = 0; r < 4; r++) {
            int R = rt*16 + quad*4 + r;
            float v = acc[rt][r] + bs[R];
            unsigned short* dst = (R < 16) ? &f[(size_t)(b*DQK + R)*HWN]
                                : (R < 32) ? &g[(size_t)(b*DQK + R-16)*HWN]
                                           : &h[(size_t)(b*CH  + R-32)*HWN];
            dst[px0 + w*16 + l15] = f2bf(v);
        }
    }
}

// ---------------- kernel 2: MFMA flash attention, pipelined ----------------
// Same fragment math as R2; double-buffered hA/fB with register prefetch so
// global->LDS latency is off the barrier critical path. 2 barriers/iter.
__global__ __launch_bounds__(256) void attn_kernel(
    const unsigned short* __restrict__ f, const unsigned short* __restrict__ g,
    const unsigned short* __restrict__ h, const float* __restrict__ x,
    const float* __restrict__ gamma_p, float* __restrict__ out)
{
    const int t    = threadIdx.x;
    const int b    = blockIdx.x & 7;        // batch -> XCD pin (L2 locality)
    const int q0   = (blockIdx.x >> 3) * QT;
    const int lane = t & 63;
    const int w    = t >> 6;
    const int l15  = lane & 15;
    const int quad = lane >> 4;

    __shared__ __align__(16) unsigned short hA[2][16][64][8];  // 32 KB
    __shared__ __align__(16) unsigned short fB[2][2][64][8];   //  4 KB
    __shared__ __align__(16) unsigned short pB[4][64][8];      //  4 KB
    __shared__ float l_l[QT];

    // zero fB (k>=16 rows must stay zero; staging only writes k<16 rows)
    for (int i = t; i < 2*2*64*8; i += 256) ((unsigned short*)fB)[i] = 0;

    // g A-frag held in regs: A[q=l15][k=quad*8+j], zero-padded k>=16
    union { short8 v; unsigned short u[8]; } gfrag;
    #pragma unroll
    for (int j = 0; j < 8; j++) {
        int k = quad*8 + j;
        gfrag.u[j] = (k < DQK) ? g[(size_t)(b*DQK + k)*HWN + q0 + w*16 + l15] : (unsigned short)0;
    }

    // prefetch regs + staging maps
    uint4 hreg[4];
    unsigned int freg;
    const int hc  = t >> 2;          // used with it-offset below
    auto load_tile = [&](int m0) {
        #pragma unroll
        for (int it = 0; it < 4; it++) {
            int idx = it*256 + t;
            int c = idx >> 2, ms = idx & 3;
            hreg[it] = *(const uint4*)&h[(size_t)(b*CH + c)*HWN + m0 + ms*8];
        }
        freg = *(const unsigned int*)&f[(size_t)(b*DQK + (t >> 4))*HWN + m0 + (t & 15)*2];
    };
    auto write_tile = [&](int buf) {
        #pragma unroll
        for (int it = 0; it < 4; it++) {
            int idx = it*256 + t;
            int c = idx >> 2, ms = idx & 3;
            *(uint4*)&hA[buf][c >> 4][ms*16 + (c & 15)][0] = hreg[it];
        }
        int k = t >> 4, m2 = (t & 15)*2;
        int row = (k >> 3)*16 + (m2 & 15);
        fB[buf][m2 >> 4][row    ][k & 7] = (unsigned short)(freg & 0xFFFF);
        fB[buf][m2 >> 4][row + 1][k & 7] = (unsigned short)(freg >> 16);
    };

    float4v acc[4][4];
    #pragma unroll
    for (int i = 0; i < 4; i++)
        #pragma unroll
        for (int j = 0; j < 4; j++) acc[i][j] = (float4v){0.f,0.f,0.f,0.f};
    float l_acc[4] = {0.f, 0.f, 0.f, 0.f};

    load_tile(0);
    write_tile(0);
    load_tile(MT);

    for (int i = 0; i < HWN/MT; i++) {
        int buf = i & 1;
        // A: write tile i+1 -> buf^1, prefetch tile i+2 (wrapped; last writes unused)
        write_tile(buf ^ 1);
        load_tile(((i + 2) & (HWN/MT - 1)) * MT);

        // B: S = g^T f on buf (wave w: its 16 q x 32 m)
        short8 fb0 = *(short8*)&fB[buf][0][lane][0];
        short8 fb1 = *(short8*)&fB[buf][1][lane][0];
        float4v s0 = {0.f,0.f,0.f,0.f}, s1 = {0.f,0.f,0.f,0.f};
        s0 = __builtin_amdgcn_mfma_f32_16x16x32_bf16(gfrag.v, fb0, s0, 0, 0, 0);
        s1 = __builtin_amdgcn_mfma_f32_16x16x32_bf16(gfrag.v, fb1, s1, 0, 0, 0);

        float pv0[4], pv1[4], rs[4];
        #pragma unroll
        for (int r = 0; r < 4; r++) {
            pv0[r] = __expf(s0[r]);
            pv1[r] = __expf(s1[r]);
            rs[r]  = pv0[r] + pv1[r];
        }
        #pragma unroll
        for (int off = 1; off <= 8; off <<= 1)
            #pragma unroll
            for (int r = 0; r < 4; r++) rs[r] += __shfl_xor(rs[r], off, 64);
        #pragma unroll
        for (int r = 0; r < 4; r++) l_acc[r] += rs[r];   // valid in all lanes

        #pragma unroll
        for (int r = 0; r < 4; r++) {
            int q15 = quad*4 + r;
            pB[w][(l15 >> 3)*16 + q15][l15 & 7]       = f2bf(pv0[r]);  // m = l15
            pB[w][(2 + (l15 >> 3))*16 + q15][l15 & 7] = f2bf(pv1[r]);  // m = 16+l15
        }
        __syncthreads();   // C: pB + staged buf^1 visible

        // D: PV — wave w: c in [w*64, w*64+64) x all 64 q
        short8 bq[4];
        #pragma unroll
        for (int qt = 0; qt < 4; qt++) bq[qt] = *(short8*)&pB[qt][lane][0];
        #pragma unroll
        for (int ct = 0; ct < 4; ct++) {
            short8 af = *(short8*)&hA[buf][w*4 + ct][lane][0];
            #pragma unroll
            for (int qt = 0; qt < 4; qt++)
                acc[ct][qt] = __builtin_amdgcn_mfma_f32_16x16x32_bf16(af, bq[qt], acc[ct][qt], 0, 0, 0);
        }
        __syncthreads();   // E: all reads of buf/pB done (WAR)
    }

    // epilogue
    if (l15 == 0) {
        #pragma unroll
        for (int r = 0; r < 4; r++) l_l[w*16 + quad*4 + r] = l_acc[r];
    }
    __syncthreads();

    const float gamma = *gamma_p;
    float linv[4];
    #pragma unroll
    for (int qt = 0; qt < 4; qt++) linv[qt] = 1.f / l_l[qt*16 + l15];
    #pragma unroll
    for (int ct = 0; ct < 4; ct++) {
        #pragma unroll
        for (int r = 0; r < 4; r++) {
            int c = w*64 + ct*16 + quad*4 + r;
            size_t base = (size_t)(b*CH + c)*HWN + q0;
            #pragma unroll
            for (int qt = 0; qt < 4; qt++) {
                size_t o = base + qt*16 + l15;
                out[o] = gamma * acc[ct][qt][r] * linv[qt] + x[o];
            }
        }
    }
}

extern "C" void kernel_launch(void* const* d_in, const int* in_sizes, int n_in,
                              void* d_out, int out_size, void* d_ws, size_t ws_size,
                              hipStream_t stream) {
    const float* x     = (const float*)d_in[0];
    const float* Wf    = (const float*)d_in[1];
    const float* bf_   = (const float*)d_in[2];
    const float* Wg    = (const float*)d_in[3];
    const float* bg    = (const float*)d_in[4];
    const float* Wh    = (const float*)d_in[5];
    const float* bh    = (const float*)d_in[6];
    const float* gamma = (const float*)d_in[7];
    float* out = (float*)d_out;

    // ws: f,g (bf16) | h (bf16) | Wbf (bf16) | bcat (fp32)  ~ 19.0 MB
    unsigned short* f   = (unsigned short*)d_ws;
    unsigned short* g   = f + (size_t)BATCH*DQK*HWN;
    unsigned short* h   = g + (size_t)BATCH*DQK*HWN;
    unsigned short* Wbf = h + (size_t)BATCH*CH*HWN;
    float*          bcat = (float*)(Wbf + 288*CH);

    wcast_kernel<<<dim3(288), 256, 0, stream>>>(Wf, bf_, Wg, bg, Wh, bh, Wbf, bcat);

    dim3 pg(HWN/64, BATCH);
    proj_kernel<<<pg, 256, 0, stream>>>(x, Wbf, bcat, f, g, h);

    attn_kernel<<<dim3((HWN/QT)*BATCH), 256, 0, stream>>>(f, g, h, x, gamma, out);
}

// Round 4
// 240.256 us; speedup vs baseline: 8.2107x; 1.8512x over previous
//
#include <hip/hip_runtime.h>
#include <math.h>

#define BATCH 8
#define CH    256
#define HWN   4096
#define DQK   16

typedef __attribute__((ext_vector_type(8))) short short8;
typedef __attribute__((ext_vector_type(4))) float float4v;

__device__ __forceinline__ unsigned short f2bf(float f) {
    union { float f; unsigned int u; } v; v.f = f;
    unsigned int r = v.u + 0x7FFF + ((v.u >> 16) & 1);   // RNE
    return (unsigned short)(r >> 16);
}
__device__ __forceinline__ unsigned int pack2bf(float lo, float hi) {
    union { float f; unsigned int u; } a, b; a.f = lo; b.f = hi;
    unsigned int ra = (a.u + 0x7FFF + ((a.u >> 16) & 1)) >> 16;
    unsigned int rb = (b.u + 0x7FFF + ((b.u >> 16) & 1)) & 0xFFFF0000u;
    return ra | rb;
}

// ---------------- kernel 0: W_cat -> bf16, biases -> bcat ----------------
__global__ __launch_bounds__(256) void wcast_kernel(
    const float* __restrict__ Wf, const float* __restrict__ bf_,
    const float* __restrict__ Wg, const float* __restrict__ bg,
    const float* __restrict__ Wh, const float* __restrict__ bh,
    unsigned short* __restrict__ Wbf, float* __restrict__ bcat)
{
    const int r = blockIdx.x;   // 288 rows
    const int t = threadIdx.x;  // 256 cols
    const float* src = (r < 16) ? (Wf + r*CH) : (r < 32) ? (Wg + (r-16)*CH) : (Wh + (r-32)*CH);
    Wbf[r*CH + t] = f2bf(src[t]);
    if (t == 0) bcat[r] = (r < 16) ? bf_[r] : (r < 32) ? bg[r-16] : bh[r-32];
}

// ---------------- kernel 1: x[b][c][px] fp32 -> xt[b][px][c] bf16 ----------------
__global__ __launch_bounds__(256) void xt_kernel(const float* __restrict__ x,
                                                 unsigned short* __restrict__ xt)
{
    const int t  = threadIdx.x;
    const int p0 = blockIdx.x * 64;
    const int c0 = blockIdx.y * 64;
    const int b  = blockIdx.z;
    __shared__ unsigned short tile[64][73];   // [px][c], padded (odd stride -> bank spread)
    const int pc = t & 63;
    const int r0 = (t >> 6) * 16;
    #pragma unroll
    for (int j = 0; j < 16; j++) {
        int c = r0 + j;
        tile[pc][c] = f2bf(x[(size_t)(b*CH + c0 + c)*HWN + p0 + pc]);
    }
    __syncthreads();
    const int pr = t >> 2;
    const int cb = (t & 3) * 16;
    unsigned int outv[8];
    #pragma unroll
    for (int i = 0; i < 8; i++)
        outv[i] = (unsigned int)tile[pr][cb + 2*i] | ((unsigned int)tile[pr][cb + 2*i + 1] << 16);
    unsigned short* dst = &xt[(size_t)(b*HWN + p0 + pr)*CH + c0 + cb];
    *(uint4*)dst       = *(uint4*)&outv[0];
    *(uint4*)(dst + 8) = *(uint4*)&outv[4];
}

// ---------------- kernel 2: LDS-free MFMA projection ----------------
// C[288][4096] = Wbf @ bf16(x): A-frags direct from L2-hot Wbf, B-frags direct
// from xt. Outputs: ft (m-interleaved, k padded 32 w/ zeros), g[16][HWN],
// h2[b][mt][c][32] (m-tiled for attn's coalesced A-frag loads).
__global__ __launch_bounds__(256, 2) void proj_kernel(
    const unsigned short* __restrict__ xt, const unsigned short* __restrict__ Wbf,
    const float* __restrict__ bcat,
    unsigned short* __restrict__ ft, unsigned short* __restrict__ g,
    unsigned short* __restrict__ h2)
{
    const int t    = threadIdx.x;
    const int px0  = blockIdx.x * 64;
    const int b    = blockIdx.y;
    const int lane = t & 63, w = t >> 6, l15 = lane & 15, quad = lane >> 4;
    const int px   = px0 + w*16 + l15;

    float4v acc[18];
    #pragma unroll
    for (int rt = 0; rt < 18; rt++) acc[rt] = (float4v){0.f,0.f,0.f,0.f};

    const unsigned short* xrow = &xt[(size_t)(b*HWN + px)*CH + quad*8];
    const unsigned short* wq   = &Wbf[l15*CH + quad*8];

    #pragma unroll
    for (int ks = 0; ks < 8; ks++) {
        short8 bfrag = *(const short8*)&xrow[ks*32];
        #pragma unroll
        for (int rt = 0; rt < 18; rt++) {
            short8 afrag = *(const short8*)&wq[rt*16*CH + ks*32];
            acc[rt] = __builtin_amdgcn_mfma_f32_16x16x32_bf16(afrag, bfrag, acc[rt], 0, 0, 0);
        }
    }

    // ---- epilogue (C layout: row=quad*4+r within rt-tile, col=l15 -> px) ----
    // ft row permutation: stored row r' in [0,16) holds m=2r', [16,32) holds m=2(r'-16)+1
    const int row_ft = (px & ~31) | (((px & 31) >> 1) + (px & 1) * 16);
    {   // rt == 0 -> ft (k = quad*4+r), plus zero the k>=16 half
        float4 bv = *(const float4*)&bcat[quad*4];
        unsigned int u0 = pack2bf(acc[0][0] + bv.x, acc[0][1] + bv.y);
        unsigned int u1 = pack2bf(acc[0][2] + bv.z, acc[0][3] + bv.w);
        unsigned short* fp = &ft[((size_t)b*HWN + row_ft)*32];
        *(uint2*)&fp[quad*4]      = make_uint2(u0, u1);
        *(uint2*)&fp[16 + quad*4] = make_uint2(0u, 0u);
    }
    {   // rt == 1 -> g rows 0..15
        float4 bv = *(const float4*)&bcat[16 + quad*4];
        float vb[4] = {bv.x, bv.y, bv.z, bv.w};
        #pragma unroll
        for (int r = 0; r < 4; r++)
            g[(size_t)(b*DQK + quad*4 + r)*HWN + px] = f2bf(acc[1][r] + vb[r]);
    }
    const int mt = px >> 5, mm = px & 31;
    #pragma unroll
    for (int rt = 2; rt < 18; rt++) {
        float4 bv = *(const float4*)&bcat[rt*16 + quad*4];
        float vb[4] = {bv.x, bv.y, bv.z, bv.w};
        #pragma unroll
        for (int r = 0; r < 4; r++) {
            int c = rt*16 + quad*4 + r - 32;
            h2[(((size_t)b*128 + mt)*CH + c)*32 + mm] = f2bf(acc[rt][r] + vb[r]);
        }
    }
}

// ---------------- kernel 3: MFMA flash attention, register-resident tiles ----------------
// Per iter (32 keys): S via 2 MFMA (frags direct from ft), exp+pack (4 b32 LDS
// writes), 1 barrier, B-frag reads (4 b128), l via ones-MFMA, PV 16 MFMA with
// h A-frags direct from h2. All global loads prefetched 1 tile ahead, issued
// right AFTER the barrier so the drain never waits on them.
__global__ __launch_bounds__(256, 2) void attn_kernel(
    const unsigned short* __restrict__ ft, const unsigned short* __restrict__ g,
    const unsigned short* __restrict__ h2, const float* __restrict__ x,
    const float* __restrict__ gamma_p, float* __restrict__ out)
{
    const int t    = threadIdx.x;
    const int b    = blockIdx.x & 7;          // batch -> XCD pin
    const int q0   = (blockIdx.x >> 3) * 64;
    const int lane = t & 63, w = t >> 6, l15 = lane & 15, quad = lane >> 4;

    // pB[buf][qtile][row = q*4 + (m>>3)][slot = (m&7)>>1] ; 8 KB total
    __shared__ unsigned int pB[2][4][64][4];

    union { short8 v; unsigned short u[8]; } gfrag, ones;
    #pragma unroll
    for (int j = 0; j < 8; j++) {
        int k = quad*8 + j;
        gfrag.u[j] = (k < DQK) ? g[(size_t)(b*DQK + k)*HWN + q0 + w*16 + l15] : (unsigned short)0;
        ones.u[j]  = (l15 == 0) ? (unsigned short)0x3F80 : (unsigned short)0;
    }

    const unsigned short* ftb = ft + (size_t)b*HWN*32;
    const unsigned short* h2b = h2 + (size_t)b*128*CH*32;

    short8 fr0[2], fr1[2], hr[2][4];
    fr0[0] = *(const short8*)&ftb[(size_t)(l15)*32 + quad*8];
    fr1[0] = *(const short8*)&ftb[(size_t)(16 + l15)*32 + quad*8];
    #pragma unroll
    for (int ct = 0; ct < 4; ct++)
        hr[0][ct] = *(const short8*)&h2b[(size_t)(w*64 + ct*16 + l15)*32 + quad*8];

    float4v acc[4][4], accl[4];
    #pragma unroll
    for (int i = 0; i < 4; i++) {
        accl[i] = (float4v){0.f,0.f,0.f,0.f};
        #pragma unroll
        for (int j = 0; j < 4; j++) acc[i][j] = (float4v){0.f,0.f,0.f,0.f};
    }

    for (int i0 = 0; i0 < 128; i0 += 2) {
        #pragma unroll
        for (int u = 0; u < 2; u++) {
            const int i = i0 + u;
            const int buf = u;
            // ---- S = g^T f (m columns interleaved: s0->even m, s1->odd m) ----
            float4v z = {0.f,0.f,0.f,0.f};
            float4v s0 = __builtin_amdgcn_mfma_f32_16x16x32_bf16(gfrag.v, fr0[buf], z, 0, 0, 0);
            float4v s1 = __builtin_amdgcn_mfma_f32_16x16x32_bf16(gfrag.v, fr1[buf], z, 0, 0, 0);
            // ---- p = exp(s), packed pair-write (even|odd m adjacent) ----
            unsigned int* pw = &pB[buf][w][quad*16 + (l15 >> 2)][l15 & 3];
            #pragma unroll
            for (int r = 0; r < 4; r++) {
                float pe = __expf(s0[r]);
                float po = __expf(s1[r]);
                pw[16*r] = pack2bf(pe, po);     // row += 4 per r -> +16 u32
            }
            __syncthreads();
            // ---- prefetch tile i+1 into slot buf^1 (post-barrier: drain-free) ----
            const int ni = (i + 1) & 127;
            fr0[buf^1] = *(const short8*)&ftb[((size_t)ni*32 + l15)*32 + quad*8];
            fr1[buf^1] = *(const short8*)&ftb[((size_t)ni*32 + 16 + l15)*32 + quad*8];
            #pragma unroll
            for (int ct = 0; ct < 4; ct++)
                hr[buf^1][ct] = *(const short8*)&h2b[(((size_t)ni*CH) + w*64 + ct*16 + l15)*32 + quad*8];
            // ---- B-frag reads + l-MFMA + PV ----
            short8 bq[4];
            #pragma unroll
            for (int qt = 0; qt < 4; qt++)
                bq[qt] = *(const short8*)&pB[buf][qt][l15*4 + quad][0];
            #pragma unroll
            for (int qt = 0; qt < 4; qt++)
                accl[qt] = __builtin_amdgcn_mfma_f32_16x16x32_bf16(ones.v, bq[qt], accl[qt], 0, 0, 0);
            #pragma unroll
            for (int ct = 0; ct < 4; ct++)
                #pragma unroll
                for (int qt = 0; qt < 4; qt++)
                    acc[ct][qt] = __builtin_amdgcn_mfma_f32_16x16x32_bf16(hr[buf][ct], bq[qt], acc[ct][qt], 0, 0, 0);
        }
    }

    // ---- epilogue: O = gamma*acc/l + x ----
    const float gamma = *gamma_p;
    float linv[4];
    #pragma unroll
    for (int qt = 0; qt < 4; qt++) {
        float lv = __shfl(accl[qt][0], lane & 15, 64);   // l row lives in lanes 0..15, reg 0
        linv[qt] = 1.f / lv;
    }
    #pragma unroll
    for (int ct = 0; ct < 4; ct++) {
        #pragma unroll
        for (int r = 0; r < 4; r++) {
            int c = w*64 + ct*16 + quad*4 + r;
            size_t base = (size_t)(b*CH + c)*HWN + q0;
            #pragma unroll
            for (int qt = 0; qt < 4; qt++) {
                size_t o = base + qt*16 + l15;
                out[o] = gamma * acc[ct][qt][r] * linv[qt] + x[o];
            }
        }
    }
}

extern "C" void kernel_launch(void* const* d_in, const int* in_sizes, int n_in,
                              void* d_out, int out_size, void* d_ws, size_t ws_size,
                              hipStream_t stream) {
    const float* x     = (const float*)d_in[0];
    const float* Wf    = (const float*)d_in[1];
    const float* bf_   = (const float*)d_in[2];
    const float* Wg    = (const float*)d_in[3];
    const float* bg    = (const float*)d_in[4];
    const float* Wh    = (const float*)d_in[5];
    const float* bh    = (const float*)d_in[6];
    const float* gamma = (const float*)d_in[7];
    float* out = (float*)d_out;

    // ws: xt 16MB | ft 2MB | g 1MB | h2 16MB | Wbf 147KB | bcat  ~= 35.2 MB
    unsigned short* xt  = (unsigned short*)d_ws;
    unsigned short* ft  = xt  + (size_t)BATCH*HWN*CH;
    unsigned short* g   = ft  + (size_t)BATCH*HWN*32;
    unsigned short* h2  = g   + (size_t)BATCH*DQK*HWN;
    unsigned short* Wbf = h2  + (size_t)BATCH*128*CH*32;
    float*          bcat = (float*)(Wbf + 288*CH);

    wcast_kernel<<<dim3(288), 256, 0, stream>>>(Wf, bf_, Wg, bg, Wh, bh, Wbf, bcat);
    xt_kernel<<<dim3(HWN/64, CH/64, BATCH), 256, 0, stream>>>(x, xt);
    proj_kernel<<<dim3(HWN/64, BATCH), 256, 0, stream>>>(xt, Wbf, bcat, ft, g, h2);
    attn_kernel<<<dim3((HWN/64)*BATCH), 256, 0, stream>>>(ft, g, h2, x, gamma, out);
}

// Round 6
// 222.448 us; speedup vs baseline: 8.8680x; 1.0801x over previous
//
#include <hip/hip_runtime.h>
#include <math.h>

#define BATCH 8
#define CH    256
#define HWN   4096
#define DQK   16

typedef __attribute__((ext_vector_type(8))) short short8;
typedef __attribute__((ext_vector_type(4))) float float4v;

__device__ __forceinline__ unsigned short f2bf(float f) {
    union { float f; unsigned int u; } v; v.f = f;
    unsigned int r = v.u + 0x7FFF + ((v.u >> 16) & 1);   // RNE
    return (unsigned short)(r >> 16);
}
__device__ __forceinline__ unsigned int pack2bf(float lo, float hi) {
    union { float f; unsigned int u; } a, b; a.f = lo; b.f = hi;
    unsigned int ra = (a.u + 0x7FFF + ((a.u >> 16) & 1)) >> 16;
    unsigned int rb = (b.u + 0x7FFF + ((b.u >> 16) & 1)) & 0xFFFF0000u;
    return ra | rb;
}
// ft row permutation: stored row s holds key m with s4=m2, s3=m4, s2=m3
// (bits 0,1,5+ unchanged). Makes S^T output registers align with PV B-frag
// slots in the SAME lane (no cross-lane transpose needed).
__device__ __forceinline__ int perm_ft(int m) {
    return (m & ~28) | ((m & 24) >> 1) | ((m & 4) << 2);
}

// ---------------- kernel 0: W_cat -> bf16, biases -> bcat ----------------
__global__ __launch_bounds__(256) void wcast_kernel(
    const float* __restrict__ Wf, const float* __restrict__ bf_,
    const float* __restrict__ Wg, const float* __restrict__ bg,
    const float* __restrict__ Wh, const float* __restrict__ bh,
    unsigned short* __restrict__ Wbf, float* __restrict__ bcat)
{
    const int r = blockIdx.x;   // 288 rows
    const int t = threadIdx.x;  // 256 cols
    const float* src = (r < 16) ? (Wf + r*CH) : (r < 32) ? (Wg + (r-16)*CH) : (Wh + (r-32)*CH);
    Wbf[r*CH + t] = f2bf(src[t]);
    if (t == 0) bcat[r] = (r < 16) ? bf_[r] : (r < 32) ? bg[r-16] : bh[r-32];
}

// ---------------- kernel 1: x[b][c][px] fp32 -> xt[b][px][c] bf16 ----------------
__global__ __launch_bounds__(256) void xt_kernel(const float* __restrict__ x,
                                                 unsigned short* __restrict__ xt)
{
    const int t  = threadIdx.x;
    const int p0 = blockIdx.x * 64;
    const int c0 = blockIdx.y * 64;
    const int b  = blockIdx.z;
    __shared__ unsigned short tile[64][73];
    const int pc = t & 63;
    const int r0 = (t >> 6) * 16;
    #pragma unroll
    for (int j = 0; j < 16; j++) {
        int c = r0 + j;
        tile[pc][c] = f2bf(x[(size_t)(b*CH + c0 + c)*HWN + p0 + pc]);
    }
    __syncthreads();
    const int pr = t >> 2;
    const int cb = (t & 3) * 16;
    unsigned int outv[8];
    #pragma unroll
    for (int i = 0; i < 8; i++)
        outv[i] = (unsigned int)tile[pr][cb + 2*i] | ((unsigned int)tile[pr][cb + 2*i + 1] << 16);
    unsigned short* dst = &xt[(size_t)(b*HWN + p0 + pr)*CH + c0 + cb];
    *(uint4*)dst       = *(uint4*)&outv[0];
    *(uint4*)(dst + 8) = *(uint4*)&outv[4];
}

// ---------------- kernel 2: MFMA projection (A=xt, B=W -> col=c, row=px) ----------------
// Outputs: ft[b][s][32] (s = perm_ft(m), k<16 real / k>=16 zero) for S^T A-frags;
// g[b][k][px]; h3[b][mt32][ct][512] fragment-ordered, coalesced uint2 stores.
__global__ __launch_bounds__(256, 2) void proj_kernel(
    const unsigned short* __restrict__ xt, const unsigned short* __restrict__ Wbf,
    const float* __restrict__ bcat,
    unsigned short* __restrict__ ft, unsigned short* __restrict__ g,
    unsigned short* __restrict__ h3)
{
    const int t    = threadIdx.x;
    const int px0  = blockIdx.x * 64;
    const int b    = blockIdx.y;
    const int lane = t & 63, w = t >> 6, l15 = lane & 15, quad = lane >> 4;

    float4v acc[18];
    #pragma unroll
    for (int rt = 0; rt < 18; rt++) acc[rt] = (float4v){0.f,0.f,0.f,0.f};

    const unsigned short* xrow = &xt[((size_t)(b*HWN + px0 + w*16 + l15))*CH + quad*8];
    const unsigned short* wrow = &Wbf[(size_t)l15*CH + quad*8];

    #pragma unroll
    for (int ks = 0; ks < 8; ks++) {
        short8 afrag = *(const short8*)&xrow[ks*32];
        #pragma unroll
        for (int rt = 0; rt < 18; rt++) {
            short8 bfrag = *(const short8*)&wrow[(size_t)rt*16*CH + ks*32];
            acc[rt] = __builtin_amdgcn_mfma_f32_16x16x32_bf16(afrag, bfrag, acc[rt], 0, 0, 0);
        }
    }

    const int pxl = px0 + w*16 + quad*4;      // this lane's px base (+r)
    {   // rt 0 -> ft at permuted rows: value (k=l15, m=pxl+r)
        float bv = bcat[l15];
        const int s0 = perm_ft(pxl);          // r in [0,4) only touches bits 0,1
        #pragma unroll
        for (int r = 0; r < 4; r++) {
            unsigned short* fp = &ft[((size_t)b*HWN + s0 + r)*32];
            fp[l15]      = f2bf(acc[0][r] + bv);
            fp[16 + l15] = 0;
        }
    }
    {   // rt 1 -> g: row k=l15, col px
        float bv = bcat[16 + l15];
        #pragma unroll
        for (int r = 0; r < 4; r++)
            g[(size_t)(b*DQK + l15)*HWN + pxl + r] = f2bf(acc[1][r] + bv);
    }
    // rt 2..17 -> h3 frag layout: block (mt32, c16-tile), idx = quadA*128 + l15*8 + j
    const int mt  = (px0 >> 5) + (w >> 1);
    const int sub = ((w & 1)*2 + (quad >> 1))*128 + l15*8 + (quad & 1)*4;
    #pragma unroll
    for (int rt = 2; rt < 18; rt++) {
        float bv = bcat[rt*16 + l15];
        unsigned int u0 = pack2bf(acc[rt][0] + bv, acc[rt][1] + bv);
        unsigned int u1 = pack2bf(acc[rt][2] + bv, acc[rt][3] + bv);
        *(uint2*)&h3[(((size_t)((b*128 + mt)*16 + (rt-2))) << 9) + sub] = make_uint2(u0, u1);
    }
}

// ---------------- kernel 3: MFMA flash attention ----------------
// Macro-iter = 64 keys. S^T = f^T g (4 MFMA, A-rows in perm_ft order), exp
// (fp32 l_acc in regs), packed pairs ARE the PV B-frag components (same lane,
// thanks to perm_ft) -> 2 b128 pB writes, one barrier, PV 32 MFMA with h
// A-frags direct from h3 (c-split across waves). pB double-buffered.
__global__ __launch_bounds__(256, 2) void attn_kernel(
    const unsigned short* __restrict__ ft, const unsigned short* __restrict__ g,
    const unsigned short* __restrict__ h3, const float* __restrict__ x,
    const float* __restrict__ gamma_p, float* __restrict__ out)
{
    const int t    = threadIdx.x;
    const int b    = blockIdx.x & 7;          // batch -> XCD pin
    const int q0   = (blockIdx.x >> 3) * 64;
    const int lane = t & 63, w = t >> 6, l15 = lane & 15, quad = lane >> 4;

    __shared__ __align__(16) uint4 pB[2][2][4][64];   // [buf][grp][qwave][lane] 16 KB
    __shared__ float l_l[64];

    union { short8 v; unsigned short u[8]; } gfrag;   // B[k=quad*8+j][q=l15], wave w's q
    #pragma unroll
    for (int j = 0; j < 8; j++) {
        int k = quad*8 + j;
        gfrag.u[j] = (k < DQK) ? g[(size_t)(b*DQK + k)*HWN + q0 + w*16 + l15] : (unsigned short)0;
    }

    const unsigned short* ftb = ft + (size_t)b*HWN*32;
    const unsigned short* h3b = h3 + (((size_t)b*128*16) << 9);

    short8 fr[2][4], hr[2][2][4];
    float4v acc[4][4];
    #pragma unroll
    for (int i = 0; i < 4; i++)
        #pragma unroll
        for (int j = 0; j < 4; j++) acc[i][j] = (float4v){0.f,0.f,0.f,0.f};
    float l_acc = 0.f;

    // initial loads (macro-tile 0 -> slot 0)
    #pragma unroll
    for (int mt4 = 0; mt4 < 4; mt4++)
        fr[0][mt4] = *(const short8*)&ftb[(size_t)(mt4*16 + l15)*32 + quad*8];
    #pragma unroll
    for (int grp = 0; grp < 2; grp++)
        #pragma unroll
        for (int ct = 0; ct < 4; ct++)
            hr[0][grp][ct] = *(const short8*)&h3b[(((size_t)(grp*16 + w*4 + ct)) << 9) + lane*8];

    for (int i0 = 0; i0 < 64; i0 += 2) {
        #pragma unroll
        for (int u = 0; u < 2; u++) {
            const int i = i0 + u;           // cur buffer = u (compile-time)
            // ---- S^T: 4 stored-row tiles of 16 (keys in perm_ft order) ----
            float4v z = {0.f,0.f,0.f,0.f};
            float4v s[4];
            #pragma unroll
            for (int mt4 = 0; mt4 < 4; mt4++)
                s[mt4] = __builtin_amdgcn_mfma_f32_16x16x32_bf16(fr[u][mt4], gfrag.v, z, 0, 0, 0);
            // ---- exp + fp32 l accumulate + pack pairs ----
            unsigned int P[4][2];
            #pragma unroll
            for (int mt4 = 0; mt4 < 4; mt4++) {
                float e0 = __expf(s[mt4][0]), e1 = __expf(s[mt4][1]);
                float e2 = __expf(s[mt4][2]), e3 = __expf(s[mt4][3]);
                l_acc += (e0 + e1) + (e2 + e3);
                P[mt4][0] = pack2bf(e0, e1);
                P[mt4][1] = pack2bf(e2, e3);
            }
            // ---- B-frags are register-local (perm_ft): component d = P[grp*2+(d>>1)][d&1] ----
            pB[u][0][w][lane] = make_uint4(P[0][0], P[0][1], P[1][0], P[1][1]);
            pB[u][1][w][lane] = make_uint4(P[2][0], P[2][1], P[3][0], P[3][1]);
            __syncthreads();
            // ---- prefetch next macro-tile into slot u^1 (post-barrier) ----
            const int ni = (i + 1) & 63;
            #pragma unroll
            for (int mt4 = 0; mt4 < 4; mt4++)
                fr[u^1][mt4] = *(const short8*)&ftb[(size_t)(ni*64 + mt4*16 + l15)*32 + quad*8];
            #pragma unroll
            for (int grp = 0; grp < 2; grp++)
                #pragma unroll
                for (int ct = 0; ct < 4; ct++)
                    hr[u^1][grp][ct] = *(const short8*)&h3b[(((size_t)((ni*2 + grp)*16 + w*4 + ct)) << 9) + lane*8];
            // ---- PV: 2 grp x 4 qt x 4 ct ----
            #pragma unroll
            for (int grp = 0; grp < 2; grp++) {
                #pragma unroll
                for (int qt = 0; qt < 4; qt++) {
                    union { uint4 uu; short8 v; } bq;
                    bq.uu = pB[u][grp][qt][lane];
                    #pragma unroll
                    for (int ct = 0; ct < 4; ct++)
                        acc[ct][qt] = __builtin_amdgcn_mfma_f32_16x16x32_bf16(hr[u][grp][ct], bq.v, acc[ct][qt], 0, 0, 0);
                }
            }
        }
    }

    // ---- l: reduce over quads (lane holds q=l15 partial), broadcast via LDS ----
    l_acc += __shfl_xor(l_acc, 16, 64);
    l_acc += __shfl_xor(l_acc, 32, 64);
    if (quad == 0) l_l[w*16 + l15] = l_acc;
    __syncthreads();

    const float gamma = *gamma_p;
    float linv[4];
    #pragma unroll
    for (int qt = 0; qt < 4; qt++) linv[qt] = 1.f / l_l[qt*16 + l15];
    #pragma unroll
    for (int ct = 0; ct < 4; ct++) {
        #pragma unroll
        for (int r = 0; r < 4; r++) {
            int c = (w*4 + ct)*16 + quad*4 + r;
            size_t base = (size_t)(b*CH + c)*HWN + q0;
            #pragma unroll
            for (int qt = 0; qt < 4; qt++) {
                size_t o = base + qt*16 + l15;
                out[o] = gamma * acc[ct][qt][r] * linv[qt] + x[o];
            }
        }
    }
}

extern "C" void kernel_launch(void* const* d_in, const int* in_sizes, int n_in,
                              void* d_out, int out_size, void* d_ws, size_t ws_size,
                              hipStream_t stream) {
    const float* x     = (const float*)d_in[0];
    const float* Wf    = (const float*)d_in[1];
    const float* bf_   = (const float*)d_in[2];
    const float* Wg    = (const float*)d_in[3];
    const float* bg    = (const float*)d_in[4];
    const float* Wh    = (const float*)d_in[5];
    const float* bh    = (const float*)d_in[6];
    const float* gamma = (const float*)d_in[7];
    float* out = (float*)d_out;

    // ws: xt 16.8MB | ft 2MB | g 1MB | h3 16.8MB | Wbf 147KB | bcat
    unsigned short* xt   = (unsigned short*)d_ws;
    unsigned short* ftp  = xt  + (size_t)BATCH*HWN*CH;
    unsigned short* g    = ftp + (size_t)BATCH*HWN*32;
    unsigned short* h3   = g   + (size_t)BATCH*DQK*HWN;
    unsigned short* Wbf  = h3  + (size_t)BATCH*128*16*512;
    float*          bcat = (float*)(Wbf + 288*CH);

    wcast_kernel<<<dim3(288), 256, 0, stream>>>(Wf, bf_, Wg, bg, Wh, bh, Wbf, bcat);
    xt_kernel<<<dim3(HWN/64, CH/64, BATCH), 256, 0, stream>>>(x, xt);
    proj_kernel<<<dim3(HWN/64, BATCH), 256, 0, stream>>>(xt, Wbf, bcat, ftp, g, h3);
    attn_kernel<<<dim3((HWN/64)*BATCH), 256, 0, stream>>>(ftp, g, h3, x, gamma, out);
}

// Round 7
// 220.614 us; speedup vs baseline: 8.9417x; 1.0083x over previous
//
#include <hip/hip_runtime.h>
#include <math.h>

#define BATCH 8
#define CH    256
#define HWN   4096
#define DQK   16

typedef __attribute__((ext_vector_type(8))) short short8;
typedef __attribute__((ext_vector_type(4))) float float4v;

__device__ __forceinline__ unsigned short f2bf(float f) {
    union { float f; unsigned int u; } v; v.f = f;
    unsigned int r = v.u + 0x7FFF + ((v.u >> 16) & 1);   // RNE
    return (unsigned short)(r >> 16);
}
__device__ __forceinline__ unsigned int pack2bf(float lo, float hi) {
    union { float f; unsigned int u; } a, b; a.f = lo; b.f = hi;
    unsigned int ra = (a.u + 0x7FFF + ((a.u >> 16) & 1)) >> 16;
    unsigned int rb = (b.u + 0x7FFF + ((b.u >> 16) & 1)) & 0xFFFF0000u;
    return ra | rb;
}
// ft row permutation: stored row s holds key m with s4=m2, s3=m4, s2=m3
// (bits 0,1,5+ unchanged). Makes S^T output registers align with PV B-frag
// slots in the SAME lane (no cross-lane transpose needed).
__device__ __forceinline__ int perm_ft(int m) {
    return (m & ~28) | ((m & 24) >> 1) | ((m & 4) << 2);
}

// ---------------- kernel 0: W_cat -> bf16, biases -> bcat ----------------
__global__ __launch_bounds__(256) void wcast_kernel(
    const float* __restrict__ Wf, const float* __restrict__ bf_,
    const float* __restrict__ Wg, const float* __restrict__ bg,
    const float* __restrict__ Wh, const float* __restrict__ bh,
    unsigned short* __restrict__ Wbf, float* __restrict__ bcat)
{
    const int r = blockIdx.x;   // 288 rows
    const int t = threadIdx.x;  // 256 cols
    const float* src = (r < 16) ? (Wf + r*CH) : (r < 32) ? (Wg + (r-16)*CH) : (Wh + (r-32)*CH);
    Wbf[r*CH + t] = f2bf(src[t]);
    if (t == 0) bcat[r] = (r < 16) ? bf_[r] : (r < 32) ? bg[r-16] : bh[r-32];
}

// ---------------- kernel 1: x[b][c][px] fp32 -> xt[b][px][c] bf16 ----------------
__global__ __launch_bounds__(256) void xt_kernel(const float* __restrict__ x,
                                                 unsigned short* __restrict__ xt)
{
    const int t  = threadIdx.x;
    const int p0 = blockIdx.x * 64;
    const int c0 = blockIdx.y * 64;
    const int b  = blockIdx.z;
    __shared__ unsigned short tile[64][73];
    const int pc = t & 63;
    const int r0 = (t >> 6) * 16;
    #pragma unroll
    for (int j = 0; j < 16; j++) {
        int c = r0 + j;
        tile[pc][c] = f2bf(x[(size_t)(b*CH + c0 + c)*HWN + p0 + pc]);
    }
    __syncthreads();
    const int pr = t >> 2;
    const int cb = (t & 3) * 16;
    unsigned int outv[8];
    #pragma unroll
    for (int i = 0; i < 8; i++)
        outv[i] = (unsigned int)tile[pr][cb + 2*i] | ((unsigned int)tile[pr][cb + 2*i + 1] << 16);
    unsigned short* dst = &xt[(size_t)(b*HWN + p0 + pr)*CH + c0 + cb];
    *(uint4*)dst       = *(uint4*)&outv[0];
    *(uint4*)(dst + 8) = *(uint4*)&outv[4];
}

// ---------------- kernel 2: MFMA projection, rt-split x3 ----------------
// Grid (64 px-blocks, 8 b, 3 rt-groups of 6). C[288][4096] = Wbf @ bf16(x).
// A-frags direct from xt, B-frags direct from L2-hot Wbf. Group 0 holds
// ft (rt 0, perm_ft rows) and g (rt 1); h rows -> h3 fragment layout.
__global__ __launch_bounds__(256, 6) void proj_kernel(
    const unsigned short* __restrict__ xt, const unsigned short* __restrict__ Wbf,
    const float* __restrict__ bcat,
    unsigned short* __restrict__ ft, unsigned short* __restrict__ g,
    unsigned short* __restrict__ h3)
{
    const int t      = threadIdx.x;
    const int px0    = blockIdx.x * 64;
    const int b      = blockIdx.y;
    const int rtbase = blockIdx.z * 6;
    const int lane = t & 63, w = t >> 6, l15 = lane & 15, quad = lane >> 4;

    float4v acc[6];
    #pragma unroll
    for (int rt = 0; rt < 6; rt++) acc[rt] = (float4v){0.f,0.f,0.f,0.f};

    const unsigned short* xrow = &xt[((size_t)(b*HWN + px0 + w*16 + l15))*CH + quad*8];
    const unsigned short* wrow = &Wbf[(size_t)l15*CH + quad*8];

    #pragma unroll
    for (int ks = 0; ks < 8; ks++) {
        short8 afrag = *(const short8*)&xrow[ks*32];
        #pragma unroll
        for (int rt = 0; rt < 6; rt++) {
            short8 bfrag = *(const short8*)&wrow[(size_t)(rtbase + rt)*16*CH + ks*32];
            acc[rt] = __builtin_amdgcn_mfma_f32_16x16x32_bf16(afrag, bfrag, acc[rt], 0, 0, 0);
        }
    }

    const int pxl = px0 + w*16 + quad*4;      // this lane's px base (+r)
    const int mt  = (px0 >> 5) + (w >> 1);
    const int sub = ((w & 1)*2 + (quad >> 1))*128 + l15*8 + (quad & 1)*4;
    #pragma unroll
    for (int rt = 0; rt < 6; rt++) {
        const int R = rtbase + rt;            // uniform
        if (R == 0) {                         // -> ft at perm_ft rows
            float bv = bcat[l15];
            const int s0 = perm_ft(pxl);      // r only touches bits 0,1
            #pragma unroll
            for (int r = 0; r < 4; r++) {
                unsigned short* fp = &ft[((size_t)b*HWN + s0 + r)*32];
                fp[l15]      = f2bf(acc[rt][r] + bv);
                fp[16 + l15] = 0;
            }
        } else if (R == 1) {                  // -> g
            float bv = bcat[16 + l15];
            #pragma unroll
            for (int r = 0; r < 4; r++)
                g[(size_t)(b*DQK + l15)*HWN + pxl + r] = f2bf(acc[rt][r] + bv);
        } else {                              // -> h3 frag layout
            float bv = bcat[R*16 + l15];
            unsigned int u0 = pack2bf(acc[rt][0] + bv, acc[rt][1] + bv);
            unsigned int u1 = pack2bf(acc[rt][2] + bv, acc[rt][3] + bv);
            *(uint2*)&h3[(((size_t)((b*128 + mt)*16 + (R-2))) << 9) + sub] = make_uint2(u0, u1);
        }
    }
}

// ---------------- kernel 3: MFMA flash attention, 8 waves ----------------
// Block = 512 thr, (batch, 64-q tile). Wave w = (qt=w>>1, half=w&1):
// S^T for its 16-q tile and 32-key half (2 MFMA + 8 exp + 1 b128 pB write),
// PV for c-slice w*32..w*32+31 over all 64 q (16 MFMA). One barrier per
// 64 keys; pB double-buffered; register prefetch post-barrier.
__global__ __launch_bounds__(512, 4) void attn_kernel(
    const unsigned short* __restrict__ ft, const unsigned short* __restrict__ g,
    const unsigned short* __restrict__ h3, const float* __restrict__ x,
    const float* __restrict__ gamma_p, float* __restrict__ out)
{
    const int t    = threadIdx.x;
    const int b    = blockIdx.x & 7;          // batch -> XCD pin
    const int q0   = (blockIdx.x >> 3) * 64;
    const int lane = t & 63, w = t >> 6, l15 = lane & 15, quad = lane >> 4;
    const int qt_w = w >> 1, half = w & 1;

    __shared__ __align__(16) uint4 pB[2][2][4][64];   // [buf][grp][qt][lane] 16 KB
    __shared__ float l_l[4][16][2];

    union { short8 v; unsigned short u[8]; } gfrag;   // B[k=quad*8+j][q=l15] of q-tile qt_w
    #pragma unroll
    for (int j = 0; j < 8; j++) {
        int k = quad*8 + j;
        gfrag.u[j] = (k < DQK) ? g[(size_t)(b*DQK + k)*HWN + q0 + qt_w*16 + l15] : (unsigned short)0;
    }

    const unsigned short* ftb = ft + (size_t)b*HWN*32;
    const unsigned short* h3b = h3 + ((size_t)b << 20);

    short8 fr[2][2], hr[2][2][2];
    float4v acc[2][4];
    #pragma unroll
    for (int i = 0; i < 2; i++)
        #pragma unroll
        for (int j = 0; j < 4; j++) acc[i][j] = (float4v){0.f,0.f,0.f,0.f};
    float l_acc = 0.f;

    // initial loads (macro-tile 0 -> slot 0)
    #pragma unroll
    for (int j = 0; j < 2; j++)
        fr[0][j] = *(const short8*)&ftb[(size_t)((half*2 + j)*16 + l15)*32 + quad*8];
    #pragma unroll
    for (int grp = 0; grp < 2; grp++)
        #pragma unroll
        for (int ctl = 0; ctl < 2; ctl++)
            hr[0][grp][ctl] = *(const short8*)&h3b[(((size_t)(grp*16 + w*2 + ctl)) << 9) + lane*8];

    for (int i0 = 0; i0 < 64; i0 += 2) {
        #pragma unroll
        for (int u = 0; u < 2; u++) {
            const int i = i0 + u;           // cur buffer = u (compile-time)
            // ---- S^T: this wave's 2 stored-row tiles (keys in perm_ft order) ----
            float4v z = {0.f,0.f,0.f,0.f};
            float4v s[2];
            #pragma unroll
            for (int j = 0; j < 2; j++)
                s[j] = __builtin_amdgcn_mfma_f32_16x16x32_bf16(fr[u][j], gfrag.v, z, 0, 0, 0);
            // ---- exp + fp32 l accumulate + pack pairs ----
            unsigned int P[2][2];
            #pragma unroll
            for (int j = 0; j < 2; j++) {
                float e0 = __expf(s[j][0]), e1 = __expf(s[j][1]);
                float e2 = __expf(s[j][2]), e3 = __expf(s[j][3]);
                l_acc += (e0 + e1) + (e2 + e3);
                P[j][0] = pack2bf(e0, e1);
                P[j][1] = pack2bf(e2, e3);
            }
            // ---- B-frag is register-local (perm_ft): one b128 write ----
            pB[u][half][qt_w][lane] = make_uint4(P[0][0], P[0][1], P[1][0], P[1][1]);
            __syncthreads();
            // ---- prefetch next macro-tile into slot u^1 (post-barrier) ----
            const int ni = (i + 1) & 63;
            #pragma unroll
            for (int j = 0; j < 2; j++)
                fr[u^1][j] = *(const short8*)&ftb[(size_t)(ni*64 + (half*2 + j)*16 + l15)*32 + quad*8];
            #pragma unroll
            for (int grp = 0; grp < 2; grp++)
                #pragma unroll
                for (int ctl = 0; ctl < 2; ctl++)
                    hr[u^1][grp][ctl] = *(const short8*)&h3b[(((size_t)((ni*2 + grp)*16 + w*2 + ctl)) << 9) + lane*8];
            // ---- PV: 2 grp x 4 qt x 2 ctl ----
            #pragma unroll
            for (int grp = 0; grp < 2; grp++) {
                #pragma unroll
                for (int qt = 0; qt < 4; qt++) {
                    union { uint4 uu; short8 v; } bq;
                    bq.uu = pB[u][grp][qt][lane];
                    #pragma unroll
                    for (int ctl = 0; ctl < 2; ctl++)
                        acc[ctl][qt] = __builtin_amdgcn_mfma_f32_16x16x32_bf16(hr[u][grp][ctl], bq.v, acc[ctl][qt], 0, 0, 0);
                }
            }
        }
    }

    // ---- l: reduce over quads; combine halves via LDS ----
    l_acc += __shfl_xor(l_acc, 16, 64);
    l_acc += __shfl_xor(l_acc, 32, 64);
    if (quad == 0) l_l[qt_w][l15][half] = l_acc;
    __syncthreads();

    const float gamma = *gamma_p;
    float linv[4];
    #pragma unroll
    for (int qt = 0; qt < 4; qt++) linv[qt] = 1.f / (l_l[qt][l15][0] + l_l[qt][l15][1]);
    #pragma unroll
    for (int ctl = 0; ctl < 2; ctl++) {
        #pragma unroll
        for (int r = 0; r < 4; r++) {
            int c = w*32 + ctl*16 + quad*4 + r;
            size_t base = (size_t)(b*CH + c)*HWN + q0;
            #pragma unroll
            for (int qt = 0; qt < 4; qt++) {
                size_t o = base + qt*16 + l15;
                out[o] = gamma * acc[ctl][qt][r] * linv[qt] + x[o];
            }
        }
    }
}

extern "C" void kernel_launch(void* const* d_in, const int* in_sizes, int n_in,
                              void* d_out, int out_size, void* d_ws, size_t ws_size,
                              hipStream_t stream) {
    const float* x     = (const float*)d_in[0];
    const float* Wf    = (const float*)d_in[1];
    const float* bf_   = (const float*)d_in[2];
    const float* Wg    = (const float*)d_in[3];
    const float* bg    = (const float*)d_in[4];
    const float* Wh    = (const float*)d_in[5];
    const float* bh    = (const float*)d_in[6];
    const float* gamma = (const float*)d_in[7];
    float* out = (float*)d_out;

    // ws: xt 16.8MB | ft 2MB | g 1MB | h3 16.8MB | Wbf 147KB | bcat
    unsigned short* xt   = (unsigned short*)d_ws;
    unsigned short* ftp  = xt  + (size_t)BATCH*HWN*CH;
    unsigned short* g    = ftp + (size_t)BATCH*HWN*32;
    unsigned short* h3   = g   + (size_t)BATCH*DQK*HWN;
    unsigned short* Wbf  = h3  + (size_t)BATCH*128*16*512;
    float*          bcat = (float*)(Wbf + 288*CH);

    wcast_kernel<<<dim3(288), 256, 0, stream>>>(Wf, bf_, Wg, bg, Wh, bh, Wbf, bcat);
    xt_kernel<<<dim3(HWN/64, CH/64, BATCH), 256, 0, stream>>>(x, xt);
    proj_kernel<<<dim3(HWN/64, BATCH, 3), 256, 0, stream>>>(xt, Wbf, bcat, ftp, g, h3);
    attn_kernel<<<dim3((HWN/64)*BATCH), 512, 0, stream>>>(ftp, g, h3, x, gamma, out);
}